// Round 6
// baseline (495.456 us; speedup 1.0000x reference)
//
#include <hip/hip_runtime.h>

typedef _Float16 f16;
typedef f16   f16x2  __attribute__((ext_vector_type(2)));
typedef f16   f16x8  __attribute__((ext_vector_type(8)));
typedef float f32x4  __attribute__((ext_vector_type(4)));
typedef float f32x4u __attribute__((ext_vector_type(4), aligned(4)));
typedef __fp16 h16x2 __attribute__((ext_vector_type(2)));

#define T_STEPS 512
#define INPUT   12
#define HID     20
#define BATCH   16
#define HSTR    25    // f16 stride per batch-row of H: odd => good bank spread; 20 real + 4 trash + 1 pad
#define LOG2E      1.4426950408889634f
#define TWO_LOG2E  2.8853900817779268f

// raw barrier: drain LDS ops only (x prefetch stays in flight on vmcnt)
static __device__ __forceinline__ void block_barrier() {
    asm volatile("s_waitcnt lgkmcnt(0)\n\ts_barrier" ::: "memory");
}
static __device__ __forceinline__ f16 cvt16(float a) { return (f16)a; }
static __device__ __forceinline__ f16x2 pk(float a, float b) {
    h16x2 r = __builtin_amdgcn_cvt_pkrtz(a, b);
    return __builtin_bit_cast(f16x2, r);
}

// 2 waves per chain (16 batches). 80 gate-rows padded to 96 = 6 MFMA tiles;
// wave w owns tiles 3w..3w+2 (tile 5 = zero dummy). Row-perm: row 4q+r of
// tile T = gate r of unit 4T+q  =>  lane (col,quad)'s acc regs are i,f,g,o
// of (batch=col, unit=4T+quad). Only h crosses waves, via LDS ping-pong.
__global__ __launch_bounds__(128) void lstm_kernel(
    const float* __restrict__ x,      // [8192,512,12]
    const float* __restrict__ w_ih,   // [80,12]
    const float* __restrict__ w_hh,   // [80,20]
    const float* __restrict__ b_ih,   // [80]
    const float* __restrict__ b_hh,   // [80]
    const float* __restrict__ w_out,  // [10,20]
    const float* __restrict__ b_out,  // [10]
    float* __restrict__ out)          // [8192,10]
{
    __shared__ f16 H[2][BATCH][HSTR];   // h ping-pong, 1.6 KB

    const int tid  = threadIdx.x;
    const int wid  = tid >> 6;
    const int lane = tid & 63;
    const int col  = lane & 15;        // batch
    const int quad = lane >> 4;

    // zero h(-1) buffer
    {
        f16* h0 = &H[0][0][0];
        for (int i = tid; i < BATCH * HSTR; i += 128) h0[i] = (f16)0.f;
    }

    // ---- A fragments + biases for this wave's 3 tiles (scales folded) ----
    const int   g_row = col & 3;                       // gate of this A-row
    const float sA    = (g_row == 2) ? TWO_LOG2E : -LOG2E;

    f16x8 afragW[3];
    f32x4 cbias[3];
    int   uu[3];                                       // act unit per tile
#pragma unroll
    for (int tt = 0; tt < 3; ++tt) {
        const int T = 3 * wid + tt;                    // global tile 0..5
        uu[tt] = 4 * T + quad;                         // 20..23 = trash for T==5
        f16x8 w = {};
        f32x4 cb = {};
        if (T < 5) {
            const int u_r = 4 * T + (col >> 2);        // unit of this A-row
            const int row = g_row * HID + u_r;         // original weight row
#pragma unroll
            for (int j = 0; j < 8; ++j) {
                float v = (j < 3) ? w_ih[row * INPUT + 3 * quad + j]
                                  : w_hh[row * HID + 5 * quad + (j - 3)];
                w[j] = (f16)(v * sA);
            }
            const int u_b = 4 * T + quad;
#pragma unroll
            for (int r = 0; r < 4; ++r) {
                float s = (r == 2) ? TWO_LOG2E : -LOG2E;
                cb[r] = (b_ih[r * HID + u_b] + b_hh[r * HID + u_b]) * s;
            }
        }
        afragW[tt] = w;
        cbias[tt]  = cb;
    }

    // ---- x access: misaligned dwordx4 covers x[3q..3q+2] (R5-verified) ----
    const int al_words = (quad == 0) ? 0 : (quad == 1) ? 2 : (quad == 2) ? 6 : 8;
    const int sel      = quad & 1;
    const float* xp = x + (size_t)(blockIdx.x * BATCH + col) * (T_STEPS * INPUT) + al_words;
    auto loadx = [&](int t) -> f32x4 { return *(const f32x4u*)(xp + (size_t)t * INPUT); };

    f32x4 q0 = loadx(0);               // x(0)
    f32x4 q1 = loadx(1);               // x(1)

    float cst[3] = {0.f, 0.f, 0.f};

    block_barrier();                   // H[0] zeros visible (lgkm only)

    union BF { f16x8 v; f16 e[8]; f16x2 h2[4]; } bf;

    // one step: reads H[p] (h(t-1)), writes H[p^1] (h(t)); q holds x(t)
    auto step = [&](int p, f32x4& q, int tl) {
        // h(t-1): 5 scalar u16 reads (odd stride -> clean banks)
        const f16* hr = &H[p][col][5 * quad];
        f16 hv0 = hr[0], hv1 = hr[1], hv2 = hr[2], hv3 = hr[3], hv4 = hr[4];

        // build B fragment: slots 0..2 = x(t), 3..7 = h(t-1)
        float x0 = sel ? q[1] : q[0];
        float x1 = sel ? q[2] : q[1];
        float x2 = sel ? q[3] : q[2];
        bf.h2[0] = pk(x0, x1);
        bf.e[2] = cvt16(x2);
        bf.e[3] = hv0; bf.e[4] = hv1; bf.e[5] = hv2; bf.e[6] = hv3; bf.e[7] = hv4;

        q = loadx(tl);                 // refill queue slot with x(t+2)

        f16* hw = &H[p ^ 1][col][0];
#pragma unroll
        for (int tt = 0; tt < 3; ++tt) {
            f32x4 acc = __builtin_amdgcn_mfma_f32_16x16x32_f16(afragW[tt], bf.v, cbias[tt], 0, 0, 0);
            // paired reciprocals: 5 exp2 + 3 rcp per unit (exact math)
            float ei = __builtin_amdgcn_exp2f(acc[0]);
            float ef = __builtin_amdgcn_exp2f(acc[1]);
            float eg = __builtin_amdgcn_exp2f(acc[2]);
            float eo = __builtin_amdgcn_exp2f(acc[3]);
            float di = 1.0f + ei, df = 1.0f + ef;
            float dg = 1.0f + eg, dn = 1.0f + eo;
            float r1 = __builtin_amdgcn_rcpf(di * df);
            float r2 = __builtin_amdgcn_rcpf(dg * dn);
            float ig = r1 * df;                       // sigmoid(i)
            float fg = r1 * di;                       // sigmoid(f)
            float og = r2 * dg;                       // sigmoid(o)
            float tg = __builtin_fmaf(-2.0f, r2 * dn, 1.0f);   // tanh(g)
            float c2 = __builtin_fmaf(fg, cst[tt], ig * tg);
            cst[tt] = c2;
            float ec = __builtin_amdgcn_exp2f(TWO_LOG2E * c2);
            float rc = __builtin_amdgcn_rcpf(1.0f + ec);
            float h  = og * __builtin_fmaf(-2.0f, rc, 1.0f);   // o * tanh(c)
            hw[uu[tt]] = cvt16(h);                    // trash slot for dummy tile
        }
        block_barrier();
    };

#pragma unroll 1
    for (int t = 0; t < T_STEPS; t += 2) {
        int l0 = t + 2; if (l0 > T_STEPS - 1) l0 = T_STEPS - 1;
        int l1 = t + 3; if (l1 > T_STEPS - 1) l1 = T_STEPS - 1;
        step(0, q0, l0);
        step(1, q1, l1);
    }
    // after 512 steps, h(511) sits in H[0]

    // ---- output projection ----
#pragma unroll
    for (int base = 0; base < BATCH * 10; base += 128) {
        int idx = base + tid;
        if (idx < BATCH * 10) {
            int b = idx / 10, o = idx % 10;
            float s = b_out[o];
#pragma unroll
            for (int u = 0; u < HID; ++u)
                s += (float)H[0][b][u] * w_out[o * HID + u];
            out[(size_t)(blockIdx.x * BATCH + b) * 10 + o] = s;
        }
    }
}

extern "C" void kernel_launch(void* const* d_in, const int* in_sizes, int n_in,
                              void* d_out, int out_size, void* d_ws, size_t ws_size,
                              hipStream_t stream) {
    const float* x     = (const float*)d_in[0];
    const float* w_ih  = (const float*)d_in[1];
    const float* w_hh  = (const float*)d_in[2];
    const float* b_ih  = (const float*)d_in[3];
    const float* b_hh  = (const float*)d_in[4];
    const float* w_out = (const float*)d_in[5];
    const float* b_out = (const float*)d_in[6];
    float* out = (float*)d_out;

    const int blocks = 8192 / BATCH;   // 512 blocks x 2 waves = 1024 waves = 1/SIMD
    hipLaunchKernelGGL(lstm_kernel, dim3(blocks), dim3(128), 0, stream,
                       x, w_ih, w_hh, b_ih, b_hh, w_out, b_out, out);
}